// Round 8
// baseline (874.099 us; speedup 1.0000x reference)
//
#include <hip/hip_runtime.h>
#include <cstdint>
#include <cstddef>

#define N_NODES 100000
#define N_EDGES 1600000
#define N_EVAL  200000

typedef __attribute__((ext_vector_type(8))) short bf16x8;
typedef __attribute__((ext_vector_type(4))) float f32x4;
typedef __attribute__((ext_vector_type(4))) unsigned int u32x4;
typedef __attribute__((ext_vector_type(2))) unsigned int u32x2;
typedef __attribute__((ext_vector_type(8))) unsigned short u16x8;

__device__ __forceinline__ unsigned short f2bf_rne(float f) {
    unsigned int u = __float_as_uint(f);
    unsigned int r = (u + 0x7FFFu + ((u >> 16) & 1u)) >> 16;
    return (unsigned short)r;
}
__device__ __forceinline__ float bf2f(unsigned short h) {
    return __uint_as_float(((unsigned int)h) << 16);
}
// pack fp32 -> (bf16_hi << 16) | bf16_lo (exact split the GEMM consumes)
__device__ __forceinline__ unsigned int pack_bf(float v) {
    unsigned short h = f2bf_rne(v);
    unsigned short l = f2bf_rne(v - bf2f(h));
    return ((unsigned int)h << 16) | (unsigned int)l;
}

// ---------------- degree count ----------------

__global__ void count_deg_kernel(const int* __restrict__ dst, int* __restrict__ deg, int E) {
    int i = blockIdx.x * blockDim.x + threadIdx.x;
    if (i < E) atomicAdd(&deg[dst[i]], 1);
}

// ---------------- parallel scan (3 kernels, all coalesced) ----------------

__global__ __launch_bounds__(256) void partial_sum_kernel(const int* __restrict__ deg,
                                                          int* __restrict__ blocksums, int N) {
    __shared__ int red[256];
    int t = threadIdx.x;
    int i = blockIdx.x * 256 + t;
    red[t] = (i < N) ? deg[i] : 0;
    __syncthreads();
#pragma unroll
    for (int s = 128; s > 0; s >>= 1) {
        if (t < s) red[t] += red[t + s];
        __syncthreads();
    }
    if (t == 0) blocksums[blockIdx.x] = red[0];
}

__global__ __launch_bounds__(512) void scan_blocks_kernel(const int* __restrict__ blocksums,
                                                          int* __restrict__ blockoff, int NB) {
    __shared__ int sc[512];
    int t = threadIdx.x;
    int v = (t < NB) ? blocksums[t] : 0;
    sc[t] = v;
    __syncthreads();
#pragma unroll
    for (int d = 1; d < 512; d <<= 1) {
        int add = (t >= d) ? sc[t - d] : 0;
        __syncthreads();
        sc[t] += add;
        __syncthreads();
    }
    if (t < NB) blockoff[t] = sc[t] - v;   // exclusive prefix
}

__global__ __launch_bounds__(256) void write_offsets_kernel(const int* __restrict__ deg,
                                                            const int* __restrict__ blockoff,
                                                            int* __restrict__ offsets,
                                                            int* __restrict__ cursor,
                                                            float* __restrict__ dis,
                                                            int N, int E) {
    __shared__ int sc[256];
    int t = threadIdx.x;
    int i = blockIdx.x * 256 + t;
    int d = (i < N) ? deg[i] : 0;
    sc[t] = d;
    __syncthreads();
#pragma unroll
    for (int s = 1; s < 256; s <<= 1) {
        int add = (t >= s) ? sc[t - s] : 0;
        __syncthreads();
        sc[t] += add;
        __syncthreads();
    }
    if (i < N) {
        int excl = sc[t] - d + blockoff[blockIdx.x];
        offsets[i] = excl;
        cursor[i] = excl;
        dis[i] = rsqrtf((float)d + 1.0f);
        if (i == N - 1) offsets[N] = E;
    }
}

// CSR entry packed: .x = src index, .y = bit pattern of weight
__global__ void fill_csr_kernel(const int* __restrict__ src, const int* __restrict__ dst,
                                const float* __restrict__ dis, int* __restrict__ cursor,
                                int2* __restrict__ csr, int E) {
    int e = blockIdx.x * blockDim.x + threadIdx.x;
    if (e < E) {
        int s = src[e], d = dst[e];
        int p = atomicAdd(&cursor[d], 1);
        csr[p] = make_int2(s, __float_as_int(dis[s] * dis[d]));
    }
}

// ---------------- W transpose + bf16 hi/lo split, all three weights in one launch ----------------
// W[K][N] -> Wt_hi/lo[N][K]

__device__ __forceinline__ void wsplit_one(const float* W, unsigned short* Wh, unsigned short* Wl,
                                           int idx, int K, int N) {
    int k = idx / N, n = idx - k * N;
    float v = W[idx];
    unsigned short h = f2bf_rne(v);
    Wh[(size_t)n * K + k] = h;
    Wl[(size_t)n * K + k] = f2bf_rne(v - bf2f(h));
}

__global__ void wsplit_all_kernel(const float* __restrict__ W1, unsigned short* __restrict__ W1h,
                                  unsigned short* __restrict__ W1l,
                                  const float* __restrict__ W2, unsigned short* __restrict__ W2h,
                                  unsigned short* __restrict__ W2l,
                                  const float* __restrict__ W3, unsigned short* __restrict__ W3h,
                                  unsigned short* __restrict__ W3l) {
    int idx = blockIdx.x * blockDim.x + threadIdx.x;
    if (idx < 128 * 256) {
        wsplit_one(W1, W1h, W1l, idx, 128, 256);
    } else if (idx < 128 * 256 + 256 * 256) {
        wsplit_one(W2, W2h, W2l, idx - 128 * 256, 256, 256);
    } else if (idx < 128 * 256 + 256 * 256 + 256 * 128) {
        wsplit_one(W3, W3h, W3l, idx - 128 * 256 - 256 * 256, 256, 128);
    }
}

// ---------------- split-bf16 MFMA GEMM, 2-phase reg-prefetch ----------------
// A is PACKED hi/lo bf16 (u32 per element); W pre-split [N][K].
// BM=128, BN template (256: 512thr/8 waves, A read once; 128: 256thr/4 waves).
// BK=32, 16x16x32 bf16 MFMA, 3 products (hh, lh, hl).

#define KP 40

template <int BN, bool BIAS, bool RELU, bool PACKOUT>
__global__ __launch_bounds__(BN == 256 ? 512 : 256, BN == 256 ? 1 : 2)
void gemm_bf16split_kernel(
    const unsigned int* __restrict__ A,
    const unsigned short* __restrict__ Wt_hi,
    const unsigned short* __restrict__ Wt_lo,
    void* __restrict__ Cout, int M, int N, int K,
    const float* __restrict__ bias)
{
    constexpr int AU = (BN == 256) ? 8 : 16;   // staged A u32 per thread
    __shared__ unsigned short As_hi[128][KP];
    __shared__ unsigned short As_lo[128][KP];
    __shared__ unsigned short Bs_hi[BN][KP];
    __shared__ unsigned short Bs_lo[BN][KP];

    const int tid = threadIdx.x;
    const int m0 = blockIdx.x * 128;
    const int n0 = blockIdx.y * BN;
    const int lane = tid & 63;
    const int wave = tid >> 6;
    const int wm0 = (BN == 256) ? (wave >> 2) * 64 : (wave >> 1) * 64;
    const int wn0 = (BN == 256) ? (wave & 3) * 64 : (wave & 1) * 64;
    const int fr = lane & 15;
    const int fk = (lane >> 4) * 8;

    f32x4 acc[4][4];
#pragma unroll
    for (int i = 0; i < 4; ++i)
#pragma unroll
        for (int j = 0; j < 4; ++j) acc[i][j] = (f32x4){0.f, 0.f, 0.f, 0.f};

    // staging geometry
    const int srowA = (BN == 256) ? (tid >> 2) : (tid >> 1);        // 0..127
    const int scA   = (BN == 256) ? (tid & 3) * 8 : (tid & 1) * 16; // u32 col
    const int srowB = tid >> 1;                                     // 0..BN-1
    const int scB   = (tid & 1) * 16;                               // u16 col

    const int agrow = m0 + srowA;
    const unsigned int* Ap = A + (size_t)agrow * K + scA;
    const unsigned short* Bh = Wt_hi + (size_t)(n0 + srowB) * K + scB;
    const unsigned short* Bl = Wt_lo + (size_t)(n0 + srowB) * K + scB;

    unsigned int ua[AU];
    u16x8 rbh[2], rbl[2];

#define LOADG(K0)                                                       \
    do {                                                                \
        if (agrow < M) {                                                \
            _Pragma("unroll")                                           \
            for (int z = 0; z < AU / 4; ++z)                            \
                *(u32x4*)(ua + 4 * z) = *(const u32x4*)(Ap + (K0) + 4 * z); \
        } else {                                                        \
            _Pragma("unroll") for (int z = 0; z < AU; ++z) ua[z] = 0u;  \
        }                                                               \
        rbh[0] = *(const u16x8*)(Bh + (K0));                            \
        rbh[1] = *(const u16x8*)(Bh + (K0) + 8);                        \
        rbl[0] = *(const u16x8*)(Bl + (K0));                            \
        rbl[1] = *(const u16x8*)(Bl + (K0) + 8);                        \
    } while (0)

    LOADG(0);
    const int niter = K >> 5;

    for (int it = 0; it < niter; ++it) {
        // ---- write staged regs to LDS ----
        unsigned short h[AU], l[AU];
#pragma unroll
        for (int i = 0; i < AU; ++i) {
            h[i] = (unsigned short)(ua[i] >> 16);
            l[i] = (unsigned short)(ua[i] & 0xFFFFu);
        }
        if constexpr (BN == 256) {
            *(u16x8*)&As_hi[srowA][scA] = *(const u16x8*)(h);
            *(u16x8*)&As_lo[srowA][scA] = *(const u16x8*)(l);
        } else {
            *(u16x8*)&As_hi[srowA][scA]     = *(const u16x8*)(h);
            *(u16x8*)&As_hi[srowA][scA + 8] = *(const u16x8*)(h + 8);
            *(u16x8*)&As_lo[srowA][scA]     = *(const u16x8*)(l);
            *(u16x8*)&As_lo[srowA][scA + 8] = *(const u16x8*)(l + 8);
        }
        *(u16x8*)&Bs_hi[srowB][scB]     = rbh[0];
        *(u16x8*)&Bs_hi[srowB][scB + 8] = rbh[1];
        *(u16x8*)&Bs_lo[srowB][scB]     = rbl[0];
        *(u16x8*)&Bs_lo[srowB][scB + 8] = rbl[1];
        // ---- prefetch next K-tile into regs (flies during MFMA phase) ----
        if (it + 1 < niter) LOADG((it + 1) << 5);
        __syncthreads();

        bf16x8 af_h[4], af_l[4], bf_h[4], bf_l[4];
#pragma unroll
        for (int i = 0; i < 4; ++i) {
            af_h[i] = *(const bf16x8*)&As_hi[wm0 + i * 16 + fr][fk];
            af_l[i] = *(const bf16x8*)&As_lo[wm0 + i * 16 + fr][fk];
            bf_h[i] = *(const bf16x8*)&Bs_hi[wn0 + i * 16 + fr][fk];
            bf_l[i] = *(const bf16x8*)&Bs_lo[wn0 + i * 16 + fr][fk];
        }
#pragma unroll
        for (int i = 0; i < 4; ++i)
#pragma unroll
            for (int j = 0; j < 4; ++j) {
                acc[i][j] = __builtin_amdgcn_mfma_f32_16x16x32_bf16(af_h[i], bf_h[j], acc[i][j], 0, 0, 0);
                acc[i][j] = __builtin_amdgcn_mfma_f32_16x16x32_bf16(af_l[i], bf_h[j], acc[i][j], 0, 0, 0);
                acc[i][j] = __builtin_amdgcn_mfma_f32_16x16x32_bf16(af_h[i], bf_l[j], acc[i][j], 0, 0, 0);
            }
        __syncthreads();
    }
#undef LOADG

    float* Cf = (float*)Cout;
    unsigned int* Cp = (unsigned int*)Cout;
#pragma unroll
    for (int j = 0; j < 4; ++j) {
        const int col = n0 + wn0 + j * 16 + fr;
        const float bb = BIAS ? bias[col] : 0.f;
#pragma unroll
        for (int i = 0; i < 4; ++i) {
            const int rbase = m0 + wm0 + i * 16 + (lane >> 4) * 4;
#pragma unroll
            for (int r = 0; r < 4; ++r) {
                const int row = rbase + r;
                if (row < M) {
                    float v = acc[i][j][r] + bb;
                    if (RELU) v = fmaxf(v, 0.f);
                    if (PACKOUT) Cp[(size_t)row * N + col] = pack_bf(v);
                    else         Cf[(size_t)row * N + col] = v;
                }
            }
        }
    }
}

// ---------------- aggregation (one wave per node, 4x edge unroll) ----------------

template <int VEC>
__device__ __forceinline__ void vload(float (&r)[VEC], const float* __restrict__ p) {
    if constexpr (VEC == 4) {
        float4 v = *(const float4*)p;
        r[0] = v.x; r[1] = v.y; r[2] = v.z; r[3] = v.w;
    } else {
        float2 v = *(const float2*)p;
        r[0] = v.x; r[1] = v.y;
    }
}

template <int F, bool BIAS, bool RELU, bool PACKOUT>
__global__ __launch_bounds__(256) void aggregate_vec_kernel(
    const float* __restrict__ H,
    const int* __restrict__ offsets,
    const int2* __restrict__ csr,
    const float* __restrict__ dis,
    const float* __restrict__ bias,
    void* __restrict__ OUT, int N)
{
    constexpr int VEC = F / 64;
    const int node = blockIdx.x * 4 + (threadIdx.x >> 6);
    if (node >= N) return;
    const int lane = threadIdx.x & 63;
    const int col = lane * VEC;

    const float d = dis[node];
    float acc[VEC];
    {
        float v[VEC];
        vload<VEC>(v, H + (size_t)node * F + col);
        const float dd = d * d;
#pragma unroll
        for (int q = 0; q < VEC; ++q) acc[q] = v[q] * dd;
    }

    const int e0 = offsets[node], e1 = offsets[node + 1];
    int e = e0;
    for (; e + 4 <= e1; e += 4) {
        int2 c0 = csr[e], c1 = csr[e + 1], c2 = csr[e + 2], c3 = csr[e + 3];
        float v0[VEC], v1[VEC], v2[VEC], v3[VEC];
        vload<VEC>(v0, H + (size_t)c0.x * F + col);
        vload<VEC>(v1, H + (size_t)c1.x * F + col);
        vload<VEC>(v2, H + (size_t)c2.x * F + col);
        vload<VEC>(v3, H + (size_t)c3.x * F + col);
        const float w0 = __int_as_float(c0.y), w1 = __int_as_float(c1.y);
        const float w2 = __int_as_float(c2.y), w3 = __int_as_float(c3.y);
#pragma unroll
        for (int q = 0; q < VEC; ++q) acc[q] = fmaf(w0, v0[q], acc[q]);
#pragma unroll
        for (int q = 0; q < VEC; ++q) acc[q] = fmaf(w1, v1[q], acc[q]);
#pragma unroll
        for (int q = 0; q < VEC; ++q) acc[q] = fmaf(w2, v2[q], acc[q]);
#pragma unroll
        for (int q = 0; q < VEC; ++q) acc[q] = fmaf(w3, v3[q], acc[q]);
    }
    for (; e < e1; ++e) {
        int2 c0 = csr[e];
        float v0[VEC];
        vload<VEC>(v0, H + (size_t)c0.x * F + col);
        const float w0 = __int_as_float(c0.y);
#pragma unroll
        for (int q = 0; q < VEC; ++q) acc[q] = fmaf(w0, v0[q], acc[q]);
    }

    if (BIAS) {
        float b[VEC];
        vload<VEC>(b, bias + col);
#pragma unroll
        for (int q = 0; q < VEC; ++q) acc[q] += b[q];
    }
    if (RELU) {
#pragma unroll
        for (int q = 0; q < VEC; ++q) acc[q] = fmaxf(acc[q], 0.f);
    }

    if constexpr (PACKOUT) {
        unsigned int* op = (unsigned int*)OUT + (size_t)node * F + col;
        if constexpr (VEC == 4) {
            *(u32x4*)op = (u32x4){pack_bf(acc[0]), pack_bf(acc[1]), pack_bf(acc[2]), pack_bf(acc[3])};
        } else {
            *(u32x2*)op = (u32x2){pack_bf(acc[0]), pack_bf(acc[1])};
        }
    } else {
        float* op = (float*)OUT + (size_t)node * F + col;
        if constexpr (VEC == 4) {
            *(float4*)op = make_float4(acc[0], acc[1], acc[2], acc[3]);
        } else {
            *(float2*)op = make_float2(acc[0], acc[1]);
        }
    }
}

// ---------------- decode: 4 edges per wave, unrolled ----------------

__global__ __launch_bounds__(256) void decode_kernel(const float* __restrict__ z,
                                                     const int* __restrict__ pos,
                                                     const int* __restrict__ neg,
                                                     float* __restrict__ out)
{
    const int wave = threadIdx.x >> 6;
    const int lane = threadIdx.x & 63;
    const int ebase = (blockIdx.x * 4 + wave) * 4;
    if (ebase >= 2 * N_EVAL) return;
    int ia[4], ib[4];
#pragma unroll
    for (int q = 0; q < 4; ++q) {
        const int e = ebase + q;
        if (e < N_EVAL) { ia[q] = pos[e];          ib[q] = pos[N_EVAL + e]; }
        else            { ia[q] = neg[e - N_EVAL]; ib[q] = neg[e]; }
    }
    float2 za[4], zb[4];
#pragma unroll
    for (int q = 0; q < 4; ++q) {
        za[q] = *(const float2*)(z + (size_t)ia[q] * 128 + lane * 2);
        zb[q] = *(const float2*)(z + (size_t)ib[q] * 128 + lane * 2);
    }
    float v[4];
#pragma unroll
    for (int q = 0; q < 4; ++q) v[q] = za[q].x * zb[q].x + za[q].y * zb[q].y;
#pragma unroll
    for (int d = 32; d > 0; d >>= 1) {
#pragma unroll
        for (int q = 0; q < 4; ++q) v[q] += __shfl_xor(v[q], d);
    }
    if (lane == 0) {
#pragma unroll
        for (int q = 0; q < 4; ++q) out[ebase + q] = v[q];
    }
}

// ---------------- launch ----------------

extern "C" void kernel_launch(void* const* d_in, const int* in_sizes, int n_in,
                              void* d_out, int out_size, void* d_ws, size_t ws_size,
                              hipStream_t stream)
{
    const float* x  = (const float*)d_in[0];
    const int*   ei = (const int*)d_in[1];
    const int*  pos = (const int*)d_in[2];
    const int*  neg = (const int*)d_in[3];
    const float* W1 = (const float*)d_in[4];
    const float* b1 = (const float*)d_in[5];
    const float* W2 = (const float*)d_in[6];
    const float* b2 = (const float*)d_in[7];
    const float* W3 = (const float*)d_in[8];
    const float* b3 = (const float*)d_in[9];
    float* out = (float*)d_out;

    const int N = N_NODES, E = N_EDGES;
    const int NB = (N + 255) / 256;   // 391 scan blocks

    char* p = (char*)d_ws;
    auto alloc = [&](size_t bytes) {
        char* r = p;
        p += (bytes + 255) & ~(size_t)255;
        return r;
    };
    int*   deg       = (int*)  alloc((size_t)N * 4);
    int*   offsets   = (int*)  alloc((size_t)(N + 1) * 4);
    int*   cursor    = (int*)  alloc((size_t)N * 4);
    float* dis       = (float*)alloc((size_t)N * 4);
    int*   blocksums = (int*)  alloc((size_t)NB * 4);
    int*   blockoff  = (int*)  alloc((size_t)NB * 4);
    int2*  csr       = (int2*) alloc((size_t)E * 8);
    char*  bufA      = (char*) alloc((size_t)N * 256 * 4);   // ping
    char*  bufB      = (char*) alloc((size_t)N * 256 * 4);   // pong
    unsigned short* W1h = (unsigned short*)alloc((size_t)256 * 128 * 2);
    unsigned short* W1l = (unsigned short*)alloc((size_t)256 * 128 * 2);
    unsigned short* W2h = (unsigned short*)alloc((size_t)256 * 256 * 2);
    unsigned short* W2l = (unsigned short*)alloc((size_t)256 * 256 * 2);
    unsigned short* W3h = (unsigned short*)alloc((size_t)128 * 256 * 2);
    unsigned short* W3l = (unsigned short*)alloc((size_t)128 * 256 * 2);

    const int* src = ei;
    const int* dst = ei + E;

    const int WTOT = 128 * 256 + 256 * 256 + 256 * 128;
    wsplit_all_kernel<<<(WTOT + 255) / 256, 256, 0, stream>>>(
        W1, W1h, W1l, W2, W2h, W2l, W3, W3h, W3l);

    hipMemsetAsync(deg, 0, (size_t)N * 4, stream);
    count_deg_kernel<<<(E + 255) / 256, 256, 0, stream>>>(dst, deg, E);
    partial_sum_kernel<<<NB, 256, 0, stream>>>(deg, blocksums, N);
    scan_blocks_kernel<<<1, 512, 0, stream>>>(blocksums, blockoff, NB);
    write_offsets_kernel<<<NB, 256, 0, stream>>>(deg, blockoff, offsets, cursor, dis, N, E);
    fill_csr_kernel<<<(E + 255) / 256, 256, 0, stream>>>(src, dst, dis, cursor, csr, E);

    const int agg_grid = (N + 3) / 4;
    const int mblocks = (N + 127) / 128;

    // Layer 1: A1 = agg(x) [N,128] packed; Qp = relu(A1 @ W1 + b1) [N,256] packed
    aggregate_vec_kernel<128, false, false, true><<<agg_grid, 256, 0, stream>>>(
        x, offsets, csr, dis, nullptr, bufA, N);
    gemm_bf16split_kernel<256, true, true, true><<<dim3(mblocks, 1), 512, 0, stream>>>(
        (const unsigned int*)bufA, W1h, W1l, bufB, N, 256, 128, b1);

    // Layer 2: P = Qp @ W2 [N,256] fp32; Q2p = relu(agg(P) + b2) [N,256] packed
    gemm_bf16split_kernel<256, false, false, false><<<dim3(mblocks, 1), 512, 0, stream>>>(
        (const unsigned int*)bufB, W2h, W2l, bufA, N, 256, 256, nullptr);
    aggregate_vec_kernel<256, true, true, true><<<agg_grid, 256, 0, stream>>>(
        (const float*)bufA, offsets, csr, dis, b2, bufB, N);

    // Layer 3: P3 = Q2p @ W3 [N,128] fp32; Z = agg(P3) + b3 [N,128] fp32
    gemm_bf16split_kernel<128, false, false, false><<<dim3(mblocks, 1), 256, 0, stream>>>(
        (const unsigned int*)bufB, W3h, W3l, bufA, N, 128, 256, nullptr);
    aggregate_vec_kernel<128, true, false, false><<<agg_grid, 256, 0, stream>>>(
        (const float*)bufA, offsets, csr, dis, b3, bufB, N);

    // Decode
    decode_kernel<<<(2 * N_EVAL + 15) / 16, 256, 0, stream>>>(
        (const float*)bufB, pos, neg, out);
}

// Round 9
// 851.297 us; speedup vs baseline: 1.0268x; 1.0268x over previous
//
#include <hip/hip_runtime.h>
#include <cstdint>
#include <cstddef>

#define N_NODES 100000
#define N_EDGES 1600000
#define N_EVAL  200000

typedef __attribute__((ext_vector_type(8))) short bf16x8;
typedef __attribute__((ext_vector_type(4))) float f32x4;
typedef __attribute__((ext_vector_type(4))) unsigned int u32x4;
typedef __attribute__((ext_vector_type(2))) unsigned int u32x2;
typedef __attribute__((ext_vector_type(8))) unsigned short u16x8;

__device__ __forceinline__ unsigned short f2bf_rne(float f) {
    unsigned int u = __float_as_uint(f);
    unsigned int r = (u + 0x7FFFu + ((u >> 16) & 1u)) >> 16;
    return (unsigned short)r;
}
__device__ __forceinline__ float bf2f(unsigned short h) {
    return __uint_as_float(((unsigned int)h) << 16);
}
// pack fp32 -> (bf16_hi << 16) | bf16_lo (exact split the GEMM consumes)
__device__ __forceinline__ unsigned int pack_bf(float v) {
    unsigned short h = f2bf_rne(v);
    unsigned short l = f2bf_rne(v - bf2f(h));
    return ((unsigned int)h << 16) | (unsigned int)l;
}

// ---------------- degree count ----------------

__global__ void count_deg_kernel(const int* __restrict__ dst, int* __restrict__ deg, int E) {
    int i = blockIdx.x * blockDim.x + threadIdx.x;
    if (i < E) atomicAdd(&deg[dst[i]], 1);
}

// ---------------- parallel scan (3 kernels, all coalesced) ----------------

__global__ __launch_bounds__(256) void partial_sum_kernel(const int* __restrict__ deg,
                                                          int* __restrict__ blocksums, int N) {
    __shared__ int red[256];
    int t = threadIdx.x;
    int i = blockIdx.x * 256 + t;
    red[t] = (i < N) ? deg[i] : 0;
    __syncthreads();
#pragma unroll
    for (int s = 128; s > 0; s >>= 1) {
        if (t < s) red[t] += red[t + s];
        __syncthreads();
    }
    if (t == 0) blocksums[blockIdx.x] = red[0];
}

__global__ __launch_bounds__(512) void scan_blocks_kernel(const int* __restrict__ blocksums,
                                                          int* __restrict__ blockoff, int NB) {
    __shared__ int sc[512];
    int t = threadIdx.x;
    int v = (t < NB) ? blocksums[t] : 0;
    sc[t] = v;
    __syncthreads();
#pragma unroll
    for (int d = 1; d < 512; d <<= 1) {
        int add = (t >= d) ? sc[t - d] : 0;
        __syncthreads();
        sc[t] += add;
        __syncthreads();
    }
    if (t < NB) blockoff[t] = sc[t] - v;   // exclusive prefix
}

__global__ __launch_bounds__(256) void write_offsets_kernel(const int* __restrict__ deg,
                                                            const int* __restrict__ blockoff,
                                                            int* __restrict__ offsets,
                                                            int* __restrict__ cursor,
                                                            float* __restrict__ dis,
                                                            int N, int E) {
    __shared__ int sc[256];
    int t = threadIdx.x;
    int i = blockIdx.x * 256 + t;
    int d = (i < N) ? deg[i] : 0;
    sc[t] = d;
    __syncthreads();
#pragma unroll
    for (int s = 1; s < 256; s <<= 1) {
        int add = (t >= s) ? sc[t - s] : 0;
        __syncthreads();
        sc[t] += add;
        __syncthreads();
    }
    if (i < N) {
        int excl = sc[t] - d + blockoff[blockIdx.x];
        offsets[i] = excl;
        cursor[i] = excl;
        dis[i] = rsqrtf((float)d + 1.0f);
        if (i == N - 1) offsets[N] = E;
    }
}

// CSR entry packed: .x = src index, .y = bit pattern of weight
__global__ void fill_csr_kernel(const int* __restrict__ src, const int* __restrict__ dst,
                                const float* __restrict__ dis, int* __restrict__ cursor,
                                int2* __restrict__ csr, int E) {
    int e = blockIdx.x * blockDim.x + threadIdx.x;
    if (e < E) {
        int s = src[e], d = dst[e];
        int p = atomicAdd(&cursor[d], 1);
        csr[p] = make_int2(s, __float_as_int(dis[s] * dis[d]));
    }
}

// ---------------- W transpose + bf16 hi/lo split, all three weights in one launch ----------------
// W[K][N] -> Wt_hi/lo[N][K]

__device__ __forceinline__ void wsplit_one(const float* W, unsigned short* Wh, unsigned short* Wl,
                                           int idx, int K, int N) {
    int k = idx / N, n = idx - k * N;
    float v = W[idx];
    unsigned short h = f2bf_rne(v);
    Wh[(size_t)n * K + k] = h;
    Wl[(size_t)n * K + k] = f2bf_rne(v - bf2f(h));
}

__global__ void wsplit_all_kernel(const float* __restrict__ W1, unsigned short* __restrict__ W1h,
                                  unsigned short* __restrict__ W1l,
                                  const float* __restrict__ W2, unsigned short* __restrict__ W2h,
                                  unsigned short* __restrict__ W2l,
                                  const float* __restrict__ W3, unsigned short* __restrict__ W3h,
                                  unsigned short* __restrict__ W3l) {
    int idx = blockIdx.x * blockDim.x + threadIdx.x;
    if (idx < 128 * 256) {
        wsplit_one(W1, W1h, W1l, idx, 128, 256);
    } else if (idx < 128 * 256 + 256 * 256) {
        wsplit_one(W2, W2h, W2l, idx - 128 * 256, 256, 256);
    } else if (idx < 128 * 256 + 256 * 256 + 256 * 128) {
        wsplit_one(W3, W3h, W3l, idx - 128 * 256 - 256 * 256, 256, 128);
    }
}

// ---------------- split-bf16 MFMA GEMM, 2-phase reg-prefetch (R7 proven shape) ----------------
// A is PACKED hi/lo bf16 (u32 per element); W pre-split [N][K].
// BM=BN=128, BK=32, 256 threads (4 waves as 2x2 of 64x64), 16x16x32 bf16 MFMA, 3 products.

#define KP 40

template <bool BIAS, bool RELU, bool PACKOUT>
__global__ __launch_bounds__(256, 2) void gemm_bf16split_kernel(
    const unsigned int* __restrict__ A,
    const unsigned short* __restrict__ Wt_hi,
    const unsigned short* __restrict__ Wt_lo,
    void* __restrict__ Cout, int M, int N, int K,
    const float* __restrict__ bias)
{
    __shared__ unsigned short As_hi[128][KP];
    __shared__ unsigned short As_lo[128][KP];
    __shared__ unsigned short Bs_hi[128][KP];
    __shared__ unsigned short Bs_lo[128][KP];

    const int tid = threadIdx.x;
    const int m0 = blockIdx.x * 128;
    const int n0 = blockIdx.y * 128;
    const int lane = tid & 63;
    const int wave = tid >> 6;
    const int wm0 = (wave >> 1) * 64;
    const int wn0 = (wave & 1) * 64;
    const int fr = lane & 15;
    const int fk = (lane >> 4) * 8;

    f32x4 acc[4][4];
#pragma unroll
    for (int i = 0; i < 4; ++i)
#pragma unroll
        for (int j = 0; j < 4; ++j) acc[i][j] = (f32x4){0.f, 0.f, 0.f, 0.f};

    const int srow = tid >> 1;
    const int sc0 = (tid & 1) * 16;
    const int agrow = m0 + srow;
    const unsigned int* Ap = A + (size_t)agrow * K + sc0;
    const unsigned short* Bh = Wt_hi + (size_t)(n0 + srow) * K + sc0;
    const unsigned short* Bl = Wt_lo + (size_t)(n0 + srow) * K + sc0;

    unsigned int ua[16];
    u16x8 rbh[2], rbl[2];

#define LOADG(K0)                                                     \
    do {                                                              \
        if (agrow < M) {                                              \
            *(u32x4*)(ua)      = *(const u32x4*)(Ap + (K0));          \
            *(u32x4*)(ua + 4)  = *(const u32x4*)(Ap + (K0) + 4);      \
            *(u32x4*)(ua + 8)  = *(const u32x4*)(Ap + (K0) + 8);      \
            *(u32x4*)(ua + 12) = *(const u32x4*)(Ap + (K0) + 12);     \
        } else {                                                      \
            _Pragma("unroll") for (int z = 0; z < 16; ++z) ua[z] = 0u;\
        }                                                             \
        rbh[0] = *(const u16x8*)(Bh + (K0));                          \
        rbh[1] = *(const u16x8*)(Bh + (K0) + 8);                      \
        rbl[0] = *(const u16x8*)(Bl + (K0));                          \
        rbl[1] = *(const u16x8*)(Bl + (K0) + 8);                      \
    } while (0)

    LOADG(0);
    const int niter = K >> 5;

    for (int it = 0; it < niter; ++it) {
        // ---- write staged regs to LDS ----
        unsigned short h[16], l[16];
#pragma unroll
        for (int i = 0; i < 16; ++i) {
            h[i] = (unsigned short)(ua[i] >> 16);
            l[i] = (unsigned short)(ua[i] & 0xFFFFu);
        }
        *(u16x8*)&As_hi[srow][sc0]     = *(const u16x8*)(h);
        *(u16x8*)&As_hi[srow][sc0 + 8] = *(const u16x8*)(h + 8);
        *(u16x8*)&As_lo[srow][sc0]     = *(const u16x8*)(l);
        *(u16x8*)&As_lo[srow][sc0 + 8] = *(const u16x8*)(l + 8);
        *(u16x8*)&Bs_hi[srow][sc0]     = rbh[0];
        *(u16x8*)&Bs_hi[srow][sc0 + 8] = rbh[1];
        *(u16x8*)&Bs_lo[srow][sc0]     = rbl[0];
        *(u16x8*)&Bs_lo[srow][sc0 + 8] = rbl[1];
        // ---- prefetch next K-tile into regs (flies during MFMA phase) ----
        if (it + 1 < niter) LOADG((it + 1) << 5);
        __syncthreads();

        bf16x8 af_h[4], af_l[4], bf_h[4], bf_l[4];
#pragma unroll
        for (int i = 0; i < 4; ++i) {
            af_h[i] = *(const bf16x8*)&As_hi[wm0 + i * 16 + fr][fk];
            af_l[i] = *(const bf16x8*)&As_lo[wm0 + i * 16 + fr][fk];
            bf_h[i] = *(const bf16x8*)&Bs_hi[wn0 + i * 16 + fr][fk];
            bf_l[i] = *(const bf16x8*)&Bs_lo[wn0 + i * 16 + fr][fk];
        }
#pragma unroll
        for (int i = 0; i < 4; ++i)
#pragma unroll
            for (int j = 0; j < 4; ++j) {
                acc[i][j] = __builtin_amdgcn_mfma_f32_16x16x32_bf16(af_h[i], bf_h[j], acc[i][j], 0, 0, 0);
                acc[i][j] = __builtin_amdgcn_mfma_f32_16x16x32_bf16(af_l[i], bf_h[j], acc[i][j], 0, 0, 0);
                acc[i][j] = __builtin_amdgcn_mfma_f32_16x16x32_bf16(af_h[i], bf_l[j], acc[i][j], 0, 0, 0);
            }
        __syncthreads();
    }
#undef LOADG

    float* Cf = (float*)Cout;
    unsigned int* Cp = (unsigned int*)Cout;
#pragma unroll
    for (int j = 0; j < 4; ++j) {
        const int col = n0 + wn0 + j * 16 + fr;
        const float bb = BIAS ? bias[col] : 0.f;
#pragma unroll
        for (int i = 0; i < 4; ++i) {
            const int rbase = m0 + wm0 + i * 16 + (lane >> 4) * 4;
#pragma unroll
            for (int r = 0; r < 4; ++r) {
                const int row = rbase + r;
                if (row < M) {
                    float v = acc[i][j][r] + bb;
                    if (RELU) v = fmaxf(v, 0.f);
                    if (PACKOUT) Cp[(size_t)row * N + col] = pack_bf(v);
                    else         Cf[(size_t)row * N + col] = v;
                }
            }
        }
    }
}

// ---------------- aggregation (one wave per node, 4x edge unroll) ----------------

template <int VEC>
__device__ __forceinline__ void vload(float (&r)[VEC], const float* __restrict__ p) {
    if constexpr (VEC == 4) {
        float4 v = *(const float4*)p;
        r[0] = v.x; r[1] = v.y; r[2] = v.z; r[3] = v.w;
    } else {
        float2 v = *(const float2*)p;
        r[0] = v.x; r[1] = v.y;
    }
}

template <int F, bool BIAS, bool RELU, bool PACKOUT>
__global__ __launch_bounds__(256) void aggregate_vec_kernel(
    const float* __restrict__ H,
    const int* __restrict__ offsets,
    const int2* __restrict__ csr,
    const float* __restrict__ dis,
    const float* __restrict__ bias,
    void* __restrict__ OUT, int N)
{
    constexpr int VEC = F / 64;
    const int node = blockIdx.x * 4 + (threadIdx.x >> 6);
    if (node >= N) return;
    const int lane = threadIdx.x & 63;
    const int col = lane * VEC;

    const float d = dis[node];
    float acc[VEC];
    {
        float v[VEC];
        vload<VEC>(v, H + (size_t)node * F + col);
        const float dd = d * d;
#pragma unroll
        for (int q = 0; q < VEC; ++q) acc[q] = v[q] * dd;
    }

    const int e0 = offsets[node], e1 = offsets[node + 1];
    int e = e0;
    for (; e + 4 <= e1; e += 4) {
        int2 c0 = csr[e], c1 = csr[e + 1], c2 = csr[e + 2], c3 = csr[e + 3];
        float v0[VEC], v1[VEC], v2[VEC], v3[VEC];
        vload<VEC>(v0, H + (size_t)c0.x * F + col);
        vload<VEC>(v1, H + (size_t)c1.x * F + col);
        vload<VEC>(v2, H + (size_t)c2.x * F + col);
        vload<VEC>(v3, H + (size_t)c3.x * F + col);
        const float w0 = __int_as_float(c0.y), w1 = __int_as_float(c1.y);
        const float w2 = __int_as_float(c2.y), w3 = __int_as_float(c3.y);
#pragma unroll
        for (int q = 0; q < VEC; ++q) acc[q] = fmaf(w0, v0[q], acc[q]);
#pragma unroll
        for (int q = 0; q < VEC; ++q) acc[q] = fmaf(w1, v1[q], acc[q]);
#pragma unroll
        for (int q = 0; q < VEC; ++q) acc[q] = fmaf(w2, v2[q], acc[q]);
#pragma unroll
        for (int q = 0; q < VEC; ++q) acc[q] = fmaf(w3, v3[q], acc[q]);
    }
    for (; e < e1; ++e) {
        int2 c0 = csr[e];
        float v0[VEC];
        vload<VEC>(v0, H + (size_t)c0.x * F + col);
        const float w0 = __int_as_float(c0.y);
#pragma unroll
        for (int q = 0; q < VEC; ++q) acc[q] = fmaf(w0, v0[q], acc[q]);
    }

    if (BIAS) {
        float b[VEC];
        vload<VEC>(b, bias + col);
#pragma unroll
        for (int q = 0; q < VEC; ++q) acc[q] += b[q];
    }
    if (RELU) {
#pragma unroll
        for (int q = 0; q < VEC; ++q) acc[q] = fmaxf(acc[q], 0.f);
    }

    if constexpr (PACKOUT) {
        unsigned int* op = (unsigned int*)OUT + (size_t)node * F + col;
        if constexpr (VEC == 4) {
            *(u32x4*)op = (u32x4){pack_bf(acc[0]), pack_bf(acc[1]), pack_bf(acc[2]), pack_bf(acc[3])};
        } else {
            *(u32x2*)op = (u32x2){pack_bf(acc[0]), pack_bf(acc[1])};
        }
    } else {
        float* op = (float*)OUT + (size_t)node * F + col;
        if constexpr (VEC == 4) {
            *(float4*)op = make_float4(acc[0], acc[1], acc[2], acc[3]);
        } else {
            *(float2*)op = make_float2(acc[0], acc[1]);
        }
    }
}

// ---------------- decode: 4 edges per wave, unrolled ----------------

__global__ __launch_bounds__(256) void decode_kernel(const float* __restrict__ z,
                                                     const int* __restrict__ pos,
                                                     const int* __restrict__ neg,
                                                     float* __restrict__ out)
{
    const int wave = threadIdx.x >> 6;
    const int lane = threadIdx.x & 63;
    const int ebase = (blockIdx.x * 4 + wave) * 4;
    if (ebase >= 2 * N_EVAL) return;
    int ia[4], ib[4];
#pragma unroll
    for (int q = 0; q < 4; ++q) {
        const int e = ebase + q;
        if (e < N_EVAL) { ia[q] = pos[e];          ib[q] = pos[N_EVAL + e]; }
        else            { ia[q] = neg[e - N_EVAL]; ib[q] = neg[e]; }
    }
    float2 za[4], zb[4];
#pragma unroll
    for (int q = 0; q < 4; ++q) {
        za[q] = *(const float2*)(z + (size_t)ia[q] * 128 + lane * 2);
        zb[q] = *(const float2*)(z + (size_t)ib[q] * 128 + lane * 2);
    }
    float v[4];
#pragma unroll
    for (int q = 0; q < 4; ++q) v[q] = za[q].x * zb[q].x + za[q].y * zb[q].y;
#pragma unroll
    for (int d = 32; d > 0; d >>= 1) {
#pragma unroll
        for (int q = 0; q < 4; ++q) v[q] += __shfl_xor(v[q], d);
    }
    if (lane == 0) {
#pragma unroll
        for (int q = 0; q < 4; ++q) out[ebase + q] = v[q];
    }
}

// ---------------- launch ----------------

extern "C" void kernel_launch(void* const* d_in, const int* in_sizes, int n_in,
                              void* d_out, int out_size, void* d_ws, size_t ws_size,
                              hipStream_t stream)
{
    const float* x  = (const float*)d_in[0];
    const int*   ei = (const int*)d_in[1];
    const int*  pos = (const int*)d_in[2];
    const int*  neg = (const int*)d_in[3];
    const float* W1 = (const float*)d_in[4];
    const float* b1 = (const float*)d_in[5];
    const float* W2 = (const float*)d_in[6];
    const float* b2 = (const float*)d_in[7];
    const float* W3 = (const float*)d_in[8];
    const float* b3 = (const float*)d_in[9];
    float* out = (float*)d_out;

    const int N = N_NODES, E = N_EDGES;
    const int NB = (N + 255) / 256;   // 391 scan blocks

    char* p = (char*)d_ws;
    auto alloc = [&](size_t bytes) {
        char* r = p;
        p += (bytes + 255) & ~(size_t)255;
        return r;
    };
    int*   deg       = (int*)  alloc((size_t)N * 4);
    int*   offsets   = (int*)  alloc((size_t)(N + 1) * 4);
    int*   cursor    = (int*)  alloc((size_t)N * 4);
    float* dis       = (float*)alloc((size_t)N * 4);
    int*   blocksums = (int*)  alloc((size_t)NB * 4);
    int*   blockoff  = (int*)  alloc((size_t)NB * 4);
    int2*  csr       = (int2*) alloc((size_t)E * 8);
    char*  bufA      = (char*) alloc((size_t)N * 256 * 4);   // ping
    char*  bufB      = (char*) alloc((size_t)N * 256 * 4);   // pong
    unsigned short* W1h = (unsigned short*)alloc((size_t)256 * 128 * 2);
    unsigned short* W1l = (unsigned short*)alloc((size_t)256 * 128 * 2);
    unsigned short* W2h = (unsigned short*)alloc((size_t)256 * 256 * 2);
    unsigned short* W2l = (unsigned short*)alloc((size_t)256 * 256 * 2);
    unsigned short* W3h = (unsigned short*)alloc((size_t)128 * 256 * 2);
    unsigned short* W3l = (unsigned short*)alloc((size_t)128 * 256 * 2);

    const int* src = ei;
    const int* dst = ei + E;

    const int WTOT = 128 * 256 + 256 * 256 + 256 * 128;
    wsplit_all_kernel<<<(WTOT + 255) / 256, 256, 0, stream>>>(
        W1, W1h, W1l, W2, W2h, W2l, W3, W3h, W3l);

    hipMemsetAsync(deg, 0, (size_t)N * 4, stream);
    count_deg_kernel<<<(E + 255) / 256, 256, 0, stream>>>(dst, deg, E);
    partial_sum_kernel<<<NB, 256, 0, stream>>>(deg, blocksums, N);
    scan_blocks_kernel<<<1, 512, 0, stream>>>(blocksums, blockoff, NB);
    write_offsets_kernel<<<NB, 256, 0, stream>>>(deg, blockoff, offsets, cursor, dis, N, E);
    fill_csr_kernel<<<(E + 255) / 256, 256, 0, stream>>>(src, dst, dis, cursor, csr, E);

    const int agg_grid = (N + 3) / 4;
    const int mblocks = (N + 127) / 128;

    // Layer 1: A1 = agg(x) [N,128] packed; Qp = relu(A1 @ W1 + b1) [N,256] packed
    aggregate_vec_kernel<128, false, false, true><<<agg_grid, 256, 0, stream>>>(
        x, offsets, csr, dis, nullptr, bufA, N);
    gemm_bf16split_kernel<true, true, true><<<dim3(mblocks, 2), 256, 0, stream>>>(
        (const unsigned int*)bufA, W1h, W1l, bufB, N, 256, 128, b1);

    // Layer 2: P = Qp @ W2 [N,256] fp32; Q2p = relu(agg(P) + b2) [N,256] packed
    gemm_bf16split_kernel<false, false, false><<<dim3(mblocks, 2), 256, 0, stream>>>(
        (const unsigned int*)bufB, W2h, W2l, bufA, N, 256, 256, nullptr);
    aggregate_vec_kernel<256, true, true, true><<<agg_grid, 256, 0, stream>>>(
        (const float*)bufA, offsets, csr, dis, b2, bufB, N);

    // Layer 3: P3 = Q2p @ W3 [N,128] fp32; Z = agg(P3) + b3 [N,128] fp32
    gemm_bf16split_kernel<false, false, false><<<dim3(mblocks, 1), 256, 0, stream>>>(
        (const unsigned int*)bufB, W3h, W3l, bufA, N, 128, 256, nullptr);
    aggregate_vec_kernel<128, true, false, false><<<agg_grid, 256, 0, stream>>>(
        (const float*)bufA, offsets, csr, dis, b3, bufB, N);

    // Decode
    decode_kernel<<<(2 * N_EVAL + 15) / 16, 256, 0, stream>>>(
        (const float*)bufB, pos, neg, out);
}